// Round 21
// baseline (413.671 us; speedup 1.0000x reference)
//
#include <hip/hip_runtime.h>
#include <cstdint>

typedef _Float16 f16;
typedef __attribute__((ext_vector_type(8))) _Float16 f16x8;
typedef __attribute__((ext_vector_type(4))) _Float16 f16x4;
typedef __attribute__((ext_vector_type(4))) float f32x4;

typedef __attribute__((address_space(1))) void gvoid_t;
typedef __attribute__((address_space(3))) void lvoid_t;

// async global->LDS, 16B per lane. LDS dest wave-uniform base; HW adds lane*16.
__device__ __forceinline__ void async_copy16(void* lds, const void* g) {
  __builtin_amdgcn_global_load_lds((gvoid_t*)(uintptr_t)g, (lvoid_t*)lds, 16, 0, 0);
}

#define BARRIER()   __builtin_amdgcn_s_barrier()
#define SCHEDBAR()  __builtin_amdgcn_sched_barrier(0)
#define VMCNT(n)    do { SCHEDBAR(); asm volatile("s_waitcnt vmcnt(" #n ")"); SCHEDBAR(); } while (0)

#define MFMA16(a, b, c) __builtin_amdgcn_mfma_f32_16x16x32_f16((a), (b), (c), 0, 0, 0)

// ----------------- shared helpers (addressing + schedule macros) -----------

#define GEOM_DECLS \
  const int tid = threadIdx.x, lane = tid & 63, wave = tid >> 6;               \
  const int wr = wave >> 2, wc = wave & 3;                                     \
  const int l15 = lane & 15, lk = lane >> 4;                                   \
  int lin = blockIdx.y * gridDim.x + blockIdx.x;                               \
  const int nxy = gridDim.x * gridDim.y;                                       \
  if ((nxy & 7) == 0) lin = (lin & 7) * (nxy >> 3) + (lin >> 3);               \
  const int bx = lin % gridDim.x, by = lin / gridDim.x;                        \
  const long brow = (long)by * 256, bcol = (long)bx * 256;                     \
  const int r0  = tid >> 3;                                                    \
  const int gc8 = (tid & 7) ^ (r0 & 7);                                        \
  const int sdst = wave * 512;                                                 \
  const f16* gAa = Ab + (brow + r0) * (long)lda + gc8 * 8;                     \
  const f16* gAb = gAa + 128L * lda;                                           \
  const f16* gBa = Bb + (bcol + r0) * (long)ldb + gc8 * 8;                     \
  const f16* gBb = gBa + 128L * ldb;                                           \
  const int x8   = l15 & 7;                                                    \
  const int cb0  = (lk ^ x8) * 8;                                              \
  const int cb1  = ((4 | lk) ^ x8) * 8;                                        \
  const int lbA  = l15 * 64;                                                   \
  const int lbB  = ((wc & 1) * 64 + l15) * 64;

#define STG(BUF, G, LD, KOFF) { \
    async_copy16((BUF) + sdst,        (G) + (KOFF)); \
    async_copy16((BUF) + 4096 + sdst, (G) + 64L * (LD) + (KOFF)); }

#define RDA4(SRC, MP) { \
    af[0] = *(const f16x8*)&(SRC)[lbA + (2*(MP))   * 1024 + cb0]; \
    af[1] = *(const f16x8*)&(SRC)[lbA + (2*(MP))   * 1024 + cb1]; \
    af[2] = *(const f16x8*)&(SRC)[lbA + (2*(MP)+1) * 1024 + cb0]; \
    af[3] = *(const f16x8*)&(SRC)[lbA + (2*(MP)+1) * 1024 + cb1]; }

#define RDB8(SRC) { \
    bf[0][0] = *(const f16x8*)&(SRC)[lbB + 0 * 1024 + cb0]; \
    bf[1][0] = *(const f16x8*)&(SRC)[lbB + 0 * 1024 + cb1]; \
    bf[0][1] = *(const f16x8*)&(SRC)[lbB + 1 * 1024 + cb0]; \
    bf[1][1] = *(const f16x8*)&(SRC)[lbB + 1 * 1024 + cb1]; \
    bf[0][2] = *(const f16x8*)&(SRC)[lbB + 2 * 1024 + cb0]; \
    bf[1][2] = *(const f16x8*)&(SRC)[lbB + 2 * 1024 + cb1]; \
    bf[0][3] = *(const f16x8*)&(SRC)[lbB + 3 * 1024 + cb0]; \
    bf[1][3] = *(const f16x8*)&(SRC)[lbB + 3 * 1024 + cb1]; }

#define CLUSTER(MP) { \
    __builtin_amdgcn_s_setprio(1); \
    _Pragma("unroll") \
    for (int n = 0; n < 4; ++n) { \
      f32x4 t = MFMA16(af[0], bf[0][n], acc[2*(MP)][n]); \
      acc[2*(MP)][n] = MFMA16(af[1], bf[1][n], t); \
    } \
    _Pragma("unroll") \
    for (int n = 0; n < 4; ++n) { \
      f32x4 t = MFMA16(af[2], bf[0][n], acc[2*(MP)+1][n]); \
      acc[2*(MP)+1][n] = MFMA16(af[3], bf[1][n], t); \
    } \
    __builtin_amdgcn_s_setprio(0); }

// Deep-flight schedule (r21): 4 barrier-segments per 2 K-tiles, stage slots
// at EARLIEST-legal segment so every load has >=1.5 segments (~1800cy) before
// its wait (HBM latency ~900cy).  Slots: S0:{AH1a,AH1b}(k1) S1:{BH0a,BH0b}(k2)
// S2:{AH0a,AH0b}(k2) S3:{BH1a,BH1b}(k3).  Waits: W1=end-S1 vmcnt(4) (drains
// prev-S3 BH1 + S0 AH1; leaves S1 BH0), W2=end-S3 vmcnt(4) (drains BH0+AH0;
// leaves BH1 -> next W1).  FIFO invariant: 4 outstanding (BH1) cross iters.
// Restage legality: each buffer's reads are consumed by clusters within their
// segment (pre-barrier), and its stage slot is >=1 barrier later.
#define MAIN_LOOP(A0, A1, B0, B1, SAH1a, SAH1b, SBH0a, SBH0b, SAH0a, SAH0b, SBH1a, SBH1b) \
  for (int J = 0; J < NIT; ++J) {                                              \
    const long k1 = 128L * J + 64;                                             \
    const long k2 = 128L * J + 128;                                            \
    const long k3 = 128L * J + 192;                                            \
    const bool st = (J + 1 < NIT);                                             \
    /* S0 */                                                                   \
    RDB8(B0); RDA4(A0, 0);                                                     \
    STG(SAH1a, gAa, lda, k1);                                                  \
    CLUSTER(0);                                                                \
    RDA4(A0, 1);                                                               \
    STG(SAH1b, gAb, lda, k1);                                                  \
    CLUSTER(1);                                                                \
    BARRIER();                                                                 \
    /* S1 */                                                                   \
    RDA4(A0, 2);                                                               \
    if (st) STG(SBH0a, gBa, ldb, k2);                                          \
    CLUSTER(2);                                                                \
    RDA4(A0, 3);                                                               \
    if (st) STG(SBH0b, gBb, ldb, k2);                                          \
    CLUSTER(3);                                                                \
    if (st) { VMCNT(4); } else { VMCNT(0); }  /* W1 */                         \
    BARRIER();                                                                 \
    /* S2 */                                                                   \
    RDB8(B1); RDA4(A1, 0);                                                     \
    if (st) STG(SAH0a, gAa, lda, k2);                                          \
    CLUSTER(0);                                                                \
    RDA4(A1, 1);                                                               \
    if (st) STG(SAH0b, gAb, lda, k2);                                          \
    CLUSTER(1);                                                                \
    BARRIER();                                                                 \
    /* S3 */                                                                   \
    RDA4(A1, 2);                                                               \
    if (st) STG(SBH1a, gBa, ldb, k3);                                          \
    CLUSTER(2);                                                                \
    RDA4(A1, 3);                                                               \
    if (st) STG(SBH1b, gBb, ldb, k3);                                          \
    CLUSTER(3);                                                                \
    if (st) VMCNT(4);                        /* W2 */                          \
    BARRIER();                                                                 \
  }

// prologue: tile0 A+B (8 loads, drained) + tile1 B (4 loads, left in flight
// = steady-state entry invariant)
#define PROLOGUE(SBH0a, SBH0b, SAH0a, SAH0b, SBH1a, SBH1b) \
  STG(SBH0a, gBa, ldb, 0);  STG(SBH0b, gBb, ldb, 0);                           \
  STG(SAH0a, gAa, lda, 0);  STG(SAH0b, gAb, lda, 0);                           \
  STG(SBH1a, gBa, ldb, 64); STG(SBH1b, gBb, ldb, 64);                          \
  VMCNT(4);                                                                    \
  BARRIER();

// --------- QKV kernel (in-body __shared__, clean codegen) ------------------
__global__ __launch_bounds__(512, 2)
void gemm_qkv(const f16* __restrict__ Ab, const f16* __restrict__ Bb,
              f16* __restrict__ Cz, const float* __restrict__ bias)
{
  __shared__ f16 AH0a[8192]; __shared__ f16 AH0b[8192];
  __shared__ f16 AH1a[8192]; __shared__ f16 AH1b[8192];
  __shared__ f16 BH0a[8192]; __shared__ f16 BH0b[8192];
  __shared__ f16 BH1a[8192]; __shared__ f16 BH1b[8192];
  const int lda = 2048, ldb = 2048, ldc = 6144;
  GEOM_DECLS
  const f16* myA0 = wr ? AH0b : AH0a;
  const f16* myA1 = wr ? AH1b : AH1a;
  const f16* myB0 = (wc & 2) ? BH0b : BH0a;
  const f16* myB1 = (wc & 2) ? BH1b : BH1a;

  f32x4 acc[8][4] = {};
  f16x8 af[4], bf[2][4];
  const int NIT = 16;                        // K=2048
  PROLOGUE(BH0a, BH0b, AH0a, AH0b, BH1a, BH1b)
  MAIN_LOOP(myA0, myA1, myB0, myB1, AH1a, AH1b, BH0a, BH0b, AH0a, AH0b, BH1a, BH1b)

#pragma unroll
  for (int m = 0; m < 8; ++m) {
#pragma unroll
    for (int n = 0; n < 4; ++n) {
      const long col = bcol + wc * 64 + n * 16 + l15;
      const float bv = bias[col];
#pragma unroll
      for (int j = 0; j < 4; ++j) {
        const long row = brow + wr * 128 + m * 16 + lk * 4 + j;
        Cz[row * (long)ldc + col] = (f16)(acc[m][n][j] + bv);
      }
    }
  }
}

// --------- Smem-struct body for the fused kernels --------------------------
struct Smem {
  f16 AH0a[8192]; f16 AH0b[8192];
  f16 AH1a[8192]; f16 AH1b[8192];
  f16 BH0a[8192]; f16 BH0b[8192];
  f16 BH1a[8192]; f16 BH1b[8192];
};

// EPI=1: f16 = acc*scale; EPI=2: f16 = exp(acc*scale) + rowsum atomics;
// EPI=3: f32 = acc / rs[row] + bias[col]
template<int EPI>
__device__ __forceinline__ void gemm_body(Smem& sm,
                                          const f16* __restrict__ Ab, int lda,
                                          const f16* __restrict__ Bb, int ldb,
                                          void* __restrict__ Cz, int ldc,
                                          const float* __restrict__ bias,
                                          float* __restrict__ rs,
                                          float scale, int K)
{
  GEOM_DECLS
  const f16* myA0 = wr ? sm.AH0b : sm.AH0a;
  const f16* myA1 = wr ? sm.AH1b : sm.AH1a;
  const f16* myB0 = (wc & 2) ? sm.BH0b : sm.BH0a;
  const f16* myB1 = (wc & 2) ? sm.BH1b : sm.BH1a;

  f32x4 acc[8][4] = {};
  f16x8 af[4], bf[2][4];
  const int NIT = K >> 7;
  PROLOGUE(sm.BH0a, sm.BH0b, sm.AH0a, sm.AH0b, sm.BH1a, sm.BH1b)
  MAIN_LOOP(myA0, myA1, myB0, myB1, sm.AH1a, sm.AH1b, sm.BH0a, sm.BH0b,
            sm.AH0a, sm.AH0b, sm.BH1a, sm.BH1b)

#pragma unroll
  for (int m = 0; m < 8; ++m) {
#pragma unroll
    for (int j = 0; j < 4; ++j) {
      const long row = brow + wr * 128 + m * 16 + lk * 4 + j;
      float inv = 0.f, part = 0.f;
      if (EPI == 3) inv = 1.0f / rs[row];
#pragma unroll
      for (int n = 0; n < 4; ++n) {
        const long col = bcol + wc * 64 + n * 16 + l15;
        const float a = acc[m][n][j];
        if (EPI == 1) {
          ((f16*)Cz)[row * (long)ldc + col] = (f16)(a * scale);
        } else if (EPI == 2) {
          const float e = __expf(a * scale);
          part += e;
          ((f16*)Cz)[row * (long)ldc + col] = (f16)e;
        } else {
          ((float*)Cz)[row * (long)ldc + col] = a * inv + bias[col];
        }
      }
      if (EPI == 2) {
        part += __shfl_xor(part, 1, 16);
        part += __shfl_xor(part, 2, 16);
        part += __shfl_xor(part, 4, 16);
        part += __shfl_xor(part, 8, 16);
        if (l15 == 0) atomicAdd(&rs[row], part);
      }
    }
  }
}

// fused: z<4 -> E_z = exp(Q_z K_z^T/sqrt(H)) + rowsum;  z>=4 -> VWT = Wout@V^T
__global__ __launch_bounds__(512, 2)
void gemm_sv(const f16* __restrict__ QKV, const f16* __restrict__ Wouth,
             f16* __restrict__ SCH, f16* __restrict__ VWT,
             float* __restrict__ RS, float inv_sqrt_h)
{
  __shared__ Smem sm;
  const int z = blockIdx.z;
  const long sQ = 2048L * 6144, sS = 2048L * 2048;
  if (z < 4) {
    gemm_body<2>(sm, QKV + z * sQ, 6144, QKV + 2048 + z * sQ, 6144,
                 SCH + z * sS, 2048, nullptr, RS + z * 2048, inv_sqrt_h, 2048);
  } else {
    const int zz = z - 4;
    gemm_body<1>(sm, Wouth, 2048, QKV + 4096 + zz * sQ, 6144,
                 VWT + zz * sS, 2048, nullptr, nullptr, 1.0f, 2048);
  }
}

// out[z][q][o] = (sum_s E[z][q][s]*VWT[z][o][s]) / rowsum[z][q] + b_out[o]
__global__ __launch_bounds__(512, 2)
void gemm_out(const f16* __restrict__ SCH, const f16* __restrict__ VWT,
              float* __restrict__ out, float* __restrict__ RS,
              const float* __restrict__ b_out)
{
  __shared__ Smem sm;
  const int z = blockIdx.z;
  const long sS = 2048L * 2048;
  gemm_body<3>(sm, SCH + z * sS, 2048, VWT + z * sS, 2048,
               out + z * sS, 2048, b_out, RS + z * 2048, 1.0f, 2048);
}

// all three f32->f16 casts + rowsum zeroing (block-range partition)
__global__ void cast_all(const float* __restrict__ x,     f16* __restrict__ xh,
                         const float* __restrict__ wq,    f16* __restrict__ wqh,
                         const float* __restrict__ wo,    f16* __restrict__ woh,
                         float* __restrict__ rs)
{
  const int b = blockIdx.x;
  if (b >= 4096) {                       // 4 blocks zero rowsum[4][2048]
    float4 z4 = {0.f, 0.f, 0.f, 0.f};
    float* p = rs + (long)(b - 4096) * 2048 + threadIdx.x * 8;
    *reinterpret_cast<float4*>(p) = z4;
    *reinterpret_cast<float4*>(p + 4) = z4;
    return;
  }
  const float* in; f16* out; long n; int b0, nb;
  if (b < 2048)      { in = x;  out = xh;  n = 16777216L; b0 = 0;    nb = 2048; }
  else if (b < 3584) { in = wq; out = wqh; n = 12582912L; b0 = 2048; nb = 1536; }
  else               { in = wo; out = woh; n = 4194304L;  b0 = 3584; nb = 512;  }
  long i = ((long)(b - b0) * 256 + threadIdx.x) * 4;
  const long stride = (long)nb * 256 * 4;
  for (; i < n; i += stride) {
    const float4 v = *reinterpret_cast<const float4*>(in + i);
    f16x4 h;
    h.x = (f16)v.x; h.y = (f16)v.y; h.z = (f16)v.z; h.w = (f16)v.w;
    *reinterpret_cast<f16x4*>(out + i) = h;
  }
}

extern "C" void kernel_launch(void* const* d_in, const int* in_sizes, int n_in,
                              void* d_out, int out_size, void* d_ws, size_t ws_size,
                              hipStream_t stream) {
  const float* x     = (const float*)d_in[0];  // [4,2048,2048]
  const float* w_qkv = (const float*)d_in[1];  // [6144,2048]
  const float* b_qkv = (const float*)d_in[2];  // [6144]
  const float* w_out = (const float*)d_in[3];  // [2048,2048]
  const float* b_out = (const float*)d_in[4];  // [2048]
  float* out = (float*)d_out;                  // [4,2048,2048] f32

  char* ws = (char*)d_ws;
  f16*   Xh    = (f16*)(ws + 0);           //  33.5 MB; dead after QKV -> SCH
  f16*   Wqkvh = (f16*)(ws + 33554432L);   //  25.2 MB
  f16*   Wouth = (f16*)(ws + 58720256L);   //   8.4 MB
  f16*   QKV   = (f16*)(ws + 67108864L);   // 100.7 MB  [8192][6144]
  float* RS    = (float*)(ws + 167772160L);//  32 KB    [4][2048] rowsums
  f16*   VWT   = (f16*)(ws + 234881024L);  //  33.5 MB  [4][2048 o][2048 s]
  f16*   SCH   = Xh;                       //  33.5 MB  E = exp(scores), f16

  const float inv_sqrt_h = 0.022097086912079608f;  // 1/sqrt(2048)

  cast_all<<<4100, 256, 0, stream>>>(x, Xh, w_qkv, Wqkvh, w_out, Wouth, RS);

  // qkv = x @ w_qkv^T + b_qkv   [8192 x 6144], grid (24,32)
  gemm_qkv<<<dim3(24, 32, 1), 512, 0, stream>>>(Xh, Wqkvh, QKV, b_qkv);

  // fused: E + rowsum (z<4), VWT (z>=4)
  gemm_sv<<<dim3(8, 8, 8), 512, 0, stream>>>(QKV, Wouth, SCH, VWT, RS, inv_sqrt_h);

  // out = (E @ VWT^T) / rowsum + b_out
  gemm_out<<<dim3(8, 8, 4), 512, 0, stream>>>(SCH, VWT, out, RS, b_out);
}

// Round 22
// 412.050 us; speedup vs baseline: 1.0039x; 1.0039x over previous
//
#include <hip/hip_runtime.h>
#include <cstdint>

typedef _Float16 f16;
typedef __attribute__((ext_vector_type(8))) _Float16 f16x8;
typedef __attribute__((ext_vector_type(4))) _Float16 f16x4;
typedef __attribute__((ext_vector_type(4))) float f32x4;

typedef __attribute__((address_space(1))) void gvoid_t;
typedef __attribute__((address_space(3))) void lvoid_t;

// async global->LDS, 16B per lane. LDS dest wave-uniform base; HW adds lane*16.
__device__ __forceinline__ void async_copy16(void* lds, const void* g) {
  __builtin_amdgcn_global_load_lds((gvoid_t*)(uintptr_t)g, (lvoid_t*)lds, 16, 0, 0);
}

#define BARRIER()   __builtin_amdgcn_s_barrier()
#define SCHEDBAR()  __builtin_amdgcn_sched_barrier(0)
#define VMCNT(n)    do { SCHEDBAR(); asm volatile("s_waitcnt vmcnt(" #n ")"); SCHEDBAR(); } while (0)

#define MFMA16(a, b, c) __builtin_amdgcn_mfma_f32_16x16x32_f16((a), (b), (c), 0, 0, 0)

// ----------------- shared helpers (addressing + schedule macros) -----------

#define GEOM_DECLS \
  const int tid = threadIdx.x, lane = tid & 63, wave = tid >> 6;               \
  const int wr = wave >> 2, wc = wave & 3;                                     \
  const int l15 = lane & 15, lk = lane >> 4;                                   \
  int lin = blockIdx.y * gridDim.x + blockIdx.x;                               \
  const int nxy = gridDim.x * gridDim.y;                                       \
  if ((nxy & 7) == 0) lin = (lin & 7) * (nxy >> 3) + (lin >> 3);               \
  const int bx = lin % gridDim.x, by = lin / gridDim.x;                        \
  const long brow = (long)by * 256, bcol = (long)bx * 256;                     \
  const int r0  = tid >> 3;                                                    \
  const int gc8 = (tid & 7) ^ (r0 & 7);                                        \
  const int sdst = wave * 512;                                                 \
  const f16* gAa = Ab + (brow + r0) * (long)lda + gc8 * 8;                     \
  const f16* gAb = gAa + 128L * lda;                                           \
  const f16* gBa = Bb + (bcol + r0) * (long)ldb + gc8 * 8;                     \
  const f16* gBb = gBa + 128L * ldb;                                           \
  const int x8   = l15 & 7;                                                    \
  const int cb0  = (lk ^ x8) * 8;                                              \
  const int cb1  = ((4 | lk) ^ x8) * 8;                                        \
  const int lbA  = l15 * 64;                                                   \
  const int lbB  = ((wc & 1) * 64 + l15) * 64;

#define STG(BUF, G, LD, KOFF) { \
    async_copy16((BUF) + sdst,        (G) + (KOFF)); \
    async_copy16((BUF) + 4096 + sdst, (G) + 64L * (LD) + (KOFF)); }

#define RDA4(SRC, MP) { \
    af[0] = *(const f16x8*)&(SRC)[lbA + (2*(MP))   * 1024 + cb0]; \
    af[1] = *(const f16x8*)&(SRC)[lbA + (2*(MP))   * 1024 + cb1]; \
    af[2] = *(const f16x8*)&(SRC)[lbA + (2*(MP)+1) * 1024 + cb0]; \
    af[3] = *(const f16x8*)&(SRC)[lbA + (2*(MP)+1) * 1024 + cb1]; }

#define RDB8(SRC) { \
    bf[0][0] = *(const f16x8*)&(SRC)[lbB + 0 * 1024 + cb0]; \
    bf[1][0] = *(const f16x8*)&(SRC)[lbB + 0 * 1024 + cb1]; \
    bf[0][1] = *(const f16x8*)&(SRC)[lbB + 1 * 1024 + cb0]; \
    bf[1][1] = *(const f16x8*)&(SRC)[lbB + 1 * 1024 + cb1]; \
    bf[0][2] = *(const f16x8*)&(SRC)[lbB + 2 * 1024 + cb0]; \
    bf[1][2] = *(const f16x8*)&(SRC)[lbB + 2 * 1024 + cb1]; \
    bf[0][3] = *(const f16x8*)&(SRC)[lbB + 3 * 1024 + cb0]; \
    bf[1][3] = *(const f16x8*)&(SRC)[lbB + 3 * 1024 + cb1]; }

#define CLUSTER(MP) { \
    __builtin_amdgcn_s_setprio(1); \
    _Pragma("unroll") \
    for (int n = 0; n < 4; ++n) { \
      f32x4 t = MFMA16(af[0], bf[0][n], acc[2*(MP)][n]); \
      acc[2*(MP)][n] = MFMA16(af[1], bf[1][n], t); \
    } \
    _Pragma("unroll") \
    for (int n = 0; n < 4; ++n) { \
      f32x4 t = MFMA16(af[2], bf[0][n], acc[2*(MP)+1][n]); \
      acc[2*(MP)+1][n] = MFMA16(af[3], bf[1][n], t); \
    } \
    __builtin_amdgcn_s_setprio(0); }

// main loop (r16/r20 converged schedule): 4 barrier-segments per 2 K-tiles
#define MAIN_LOOP(A0, A1, B0, B1, SBH1b, SAH1a, SAH1b, SBH0a, SBH0b, SAH0a, SAH0b, SBH1a) \
  for (int J = 0; J < NIT; ++J) {                                              \
    const long k1 = 128L * J + 64;                                             \
    const long k2 = 128L * J + 128;                                            \
    const long k3 = 128L * J + 192;                                            \
    const bool st = (J + 1 < NIT);                                             \
    RDB8(B0); RDA4(A0, 0);                                                     \
    STG(SBH1b, gBb, ldb, k1);                                                  \
    CLUSTER(0);                                                                \
    RDA4(A0, 1);                                                               \
    STG(SAH1a, gAa, lda, k1);                                                  \
    CLUSTER(1);                                                                \
    BARRIER();                                                                 \
    RDA4(A0, 2);                                                               \
    STG(SAH1b, gAb, lda, k1);                                                  \
    CLUSTER(2);                                                                \
    RDA4(A0, 3);                                                               \
    if (st) STG(SBH0a, gBa, ldb, k2);                                          \
    CLUSTER(3);                                                                \
    if (st) { VMCNT(2); } else { VMCNT(0); }                                   \
    BARRIER();                                                                 \
    RDB8(B1); RDA4(A1, 0);                                                     \
    if (st) STG(SBH0b, gBb, ldb, k2);                                          \
    CLUSTER(0);                                                                \
    RDA4(A1, 1);                                                               \
    if (st) STG(SAH0a, gAa, lda, k2);                                          \
    CLUSTER(1);                                                                \
    BARRIER();                                                                 \
    RDA4(A1, 2);                                                               \
    if (st) STG(SAH0b, gAb, lda, k2);                                          \
    CLUSTER(2);                                                                \
    RDA4(A1, 3);                                                               \
    if (st) STG(SBH1a, gBa, ldb, k3);                                          \
    CLUSTER(3);                                                                \
    if (st) VMCNT(2);                                                          \
    BARRIER();                                                                 \
  }

#define PROLOGUE(SBH0a, SBH0b, SAH0a, SAH0b, SBH1a) \
  STG(SBH0a, gBa, ldb, 0);  STG(SBH0b, gBb, ldb, 0);                           \
  STG(SAH0a, gAa, lda, 0);  STG(SAH0b, gAb, lda, 0);                           \
  STG(SBH1a, gBa, ldb, 64);                                                    \
  VMCNT(2);                                                                    \
  BARRIER();

// --------- r16-verbatim QKV kernel (in-body __shared__, clean codegen) -----
__global__ __launch_bounds__(512, 2)
void gemm_qkv(const f16* __restrict__ Ab, const f16* __restrict__ Bb,
              f16* __restrict__ Cz, const float* __restrict__ bias)
{
  __shared__ f16 AH0a[8192]; __shared__ f16 AH0b[8192];
  __shared__ f16 AH1a[8192]; __shared__ f16 AH1b[8192];
  __shared__ f16 BH0a[8192]; __shared__ f16 BH0b[8192];
  __shared__ f16 BH1a[8192]; __shared__ f16 BH1b[8192];
  const int lda = 2048, ldb = 2048, ldc = 6144;
  GEOM_DECLS
  const f16* myA0 = wr ? AH0b : AH0a;
  const f16* myA1 = wr ? AH1b : AH1a;
  const f16* myB0 = (wc & 2) ? BH0b : BH0a;
  const f16* myB1 = (wc & 2) ? BH1b : BH1a;

  f32x4 acc[8][4] = {};
  f16x8 af[4], bf[2][4];
  const int NIT = 16;                        // K=2048
  PROLOGUE(BH0a, BH0b, AH0a, AH0b, BH1a)
  MAIN_LOOP(myA0, myA1, myB0, myB1, BH1b, AH1a, AH1b, BH0a, BH0b, AH0a, AH0b, BH1a)

#pragma unroll
  for (int m = 0; m < 8; ++m) {
#pragma unroll
    for (int n = 0; n < 4; ++n) {
      const long col = bcol + wc * 64 + n * 16 + l15;
      const float bv = bias[col];
#pragma unroll
      for (int j = 0; j < 4; ++j) {
        const long row = brow + wr * 128 + m * 16 + lk * 4 + j;
        Cz[row * (long)ldc + col] = (f16)(acc[m][n][j] + bv);
      }
    }
  }
}

// --------- Smem-struct body for the fused kernels --------------------------
struct Smem {
  f16 AH0a[8192]; f16 AH0b[8192];
  f16 AH1a[8192]; f16 AH1b[8192];
  f16 BH0a[8192]; f16 BH0b[8192];
  f16 BH1a[8192]; f16 BH1b[8192];
};

// EPI=1: f16 = acc*scale; EPI=2: f16 = exp(acc*scale) + rowsum atomics;
// EPI=3: f32 = acc / rs[row] + bias[col]
template<int EPI>
__device__ __forceinline__ void gemm_body(Smem& sm,
                                          const f16* __restrict__ Ab, int lda,
                                          const f16* __restrict__ Bb, int ldb,
                                          void* __restrict__ Cz, int ldc,
                                          const float* __restrict__ bias,
                                          float* __restrict__ rs,
                                          float scale, int K)
{
  GEOM_DECLS
  const f16* myA0 = wr ? sm.AH0b : sm.AH0a;
  const f16* myA1 = wr ? sm.AH1b : sm.AH1a;
  const f16* myB0 = (wc & 2) ? sm.BH0b : sm.BH0a;
  const f16* myB1 = (wc & 2) ? sm.BH1b : sm.BH1a;

  f32x4 acc[8][4] = {};
  f16x8 af[4], bf[2][4];
  const int NIT = K >> 7;
  PROLOGUE(sm.BH0a, sm.BH0b, sm.AH0a, sm.AH0b, sm.BH1a)
  MAIN_LOOP(myA0, myA1, myB0, myB1, sm.BH1b, sm.AH1a, sm.AH1b, sm.BH0a,
            sm.BH0b, sm.AH0a, sm.AH0b, sm.BH1a)

#pragma unroll
  for (int m = 0; m < 8; ++m) {
#pragma unroll
    for (int j = 0; j < 4; ++j) {
      const long row = brow + wr * 128 + m * 16 + lk * 4 + j;
      float inv = 0.f, part = 0.f;
      if (EPI == 3) inv = 1.0f / rs[row];
#pragma unroll
      for (int n = 0; n < 4; ++n) {
        const long col = bcol + wc * 64 + n * 16 + l15;
        const float a = acc[m][n][j];
        if (EPI == 1) {
          ((f16*)Cz)[row * (long)ldc + col] = (f16)(a * scale);
        } else if (EPI == 2) {
          const float e = __expf(a * scale);
          part += e;
          ((f16*)Cz)[row * (long)ldc + col] = (f16)e;
        } else {
          ((float*)Cz)[row * (long)ldc + col] = a * inv + bias[col];
        }
      }
      if (EPI == 2) {
        part += __shfl_xor(part, 1, 16);
        part += __shfl_xor(part, 2, 16);
        part += __shfl_xor(part, 4, 16);
        part += __shfl_xor(part, 8, 16);
        if (l15 == 0) atomicAdd(&rs[row], part);
      }
    }
  }
}

// fused: z<4 -> E_z = exp(Q_z K_z^T/sqrt(H)) + rowsum;  z>=4 -> VWT = Wout@V^T
__global__ __launch_bounds__(512, 2)
void gemm_sv(const f16* __restrict__ QKV, const f16* __restrict__ Wouth,
             f16* __restrict__ SCH, f16* __restrict__ VWT,
             float* __restrict__ RS, float inv_sqrt_h)
{
  __shared__ Smem sm;
  const int z = blockIdx.z;
  const long sQ = 2048L * 6144, sS = 2048L * 2048;
  if (z < 4) {
    gemm_body<2>(sm, QKV + z * sQ, 6144, QKV + 2048 + z * sQ, 6144,
                 SCH + z * sS, 2048, nullptr, RS + z * 2048, inv_sqrt_h, 2048);
  } else {
    const int zz = z - 4;
    gemm_body<1>(sm, Wouth, 2048, QKV + 4096 + zz * sQ, 6144,
                 VWT + zz * sS, 2048, nullptr, nullptr, 1.0f, 2048);
  }
}

// out[z][q][o] = (sum_s E[z][q][s]*VWT[z][o][s]) / rowsum[z][q] + b_out[o]
__global__ __launch_bounds__(512, 2)
void gemm_out(const f16* __restrict__ SCH, const f16* __restrict__ VWT,
              float* __restrict__ out, float* __restrict__ RS,
              const float* __restrict__ b_out)
{
  __shared__ Smem sm;
  const int z = blockIdx.z;
  const long sS = 2048L * 2048;
  gemm_body<3>(sm, SCH + z * sS, 2048, VWT + z * sS, 2048,
               out + z * sS, 2048, b_out, RS + z * 2048, 1.0f, 2048);
}

// all three f32->f16 casts + rowsum zeroing (block-range partition)
__global__ void cast_all(const float* __restrict__ x,     f16* __restrict__ xh,
                         const float* __restrict__ wq,    f16* __restrict__ wqh,
                         const float* __restrict__ wo,    f16* __restrict__ woh,
                         float* __restrict__ rs)
{
  const int b = blockIdx.x;
  if (b >= 4096) {                       // 4 blocks zero rowsum[4][2048]
    float4 z4 = {0.f, 0.f, 0.f, 0.f};
    float* p = rs + (long)(b - 4096) * 2048 + threadIdx.x * 8;
    *reinterpret_cast<float4*>(p) = z4;
    *reinterpret_cast<float4*>(p + 4) = z4;
    return;
  }
  const float* in; f16* out; long n; int b0, nb;
  if (b < 2048)      { in = x;  out = xh;  n = 16777216L; b0 = 0;    nb = 2048; }
  else if (b < 3584) { in = wq; out = wqh; n = 12582912L; b0 = 2048; nb = 1536; }
  else               { in = wo; out = woh; n = 4194304L;  b0 = 3584; nb = 512;  }
  long i = ((long)(b - b0) * 256 + threadIdx.x) * 4;
  const long stride = (long)nb * 256 * 4;
  for (; i < n; i += stride) {
    const float4 v = *reinterpret_cast<const float4*>(in + i);
    f16x4 h;
    h.x = (f16)v.x; h.y = (f16)v.y; h.z = (f16)v.z; h.w = (f16)v.w;
    *reinterpret_cast<f16x4*>(out + i) = h;
  }
}

extern "C" void kernel_launch(void* const* d_in, const int* in_sizes, int n_in,
                              void* d_out, int out_size, void* d_ws, size_t ws_size,
                              hipStream_t stream) {
  const float* x     = (const float*)d_in[0];  // [4,2048,2048]
  const float* w_qkv = (const float*)d_in[1];  // [6144,2048]
  const float* b_qkv = (const float*)d_in[2];  // [6144]
  const float* w_out = (const float*)d_in[3];  // [2048,2048]
  const float* b_out = (const float*)d_in[4];  // [2048]
  float* out = (float*)d_out;                  // [4,2048,2048] f32

  char* ws = (char*)d_ws;
  f16*   Xh    = (f16*)(ws + 0);           //  33.5 MB; dead after QKV -> SCH
  f16*   Wqkvh = (f16*)(ws + 33554432L);   //  25.2 MB
  f16*   Wouth = (f16*)(ws + 58720256L);   //   8.4 MB
  f16*   QKV   = (f16*)(ws + 67108864L);   // 100.7 MB  [8192][6144]
  float* RS    = (float*)(ws + 167772160L);//  32 KB    [4][2048] rowsums
  f16*   VWT   = (f16*)(ws + 234881024L);  //  33.5 MB  [4][2048 o][2048 s]
  f16*   SCH   = Xh;                       //  33.5 MB  E = exp(scores), f16

  const float inv_sqrt_h = 0.022097086912079608f;  // 1/sqrt(2048)

  cast_all<<<4100, 256, 0, stream>>>(x, Xh, w_qkv, Wqkvh, w_out, Wouth, RS);

  // qkv = x @ w_qkv^T + b_qkv   [8192 x 6144], grid (24,32)
  gemm_qkv<<<dim3(24, 32, 1), 512, 0, stream>>>(Xh, Wqkvh, QKV, b_qkv);

  // fused: E + rowsum (z<4), VWT (z>=4)
  gemm_sv<<<dim3(8, 8, 8), 512, 0, stream>>>(QKV, Wouth, SCH, VWT, RS, inv_sqrt_h);

  // out = (E @ VWT^T) / rowsum + b_out
  gemm_out<<<dim3(8, 8, 4), 512, 0, stream>>>(SCH, VWT, out, RS, b_out);
}